// Round 8
// baseline (69.025 us; speedup 1.0000x reference)
//
#include <hip/hip_runtime.h>
#include <math.h>

#define PI_F 3.14159265358979323846f

typedef float v2 __attribute__((ext_vector_type(2)));

__device__ __forceinline__ v2 sp(float x) { v2 r; r.x = x; r.y = x; return r; }
__device__ __forceinline__ v2 vfma(v2 a, v2 b, v2 c) {
    return __builtin_elementwise_fma(a, b, c);
}

// One 16-amp half-state per thread, packed along q4: pack k = amps 2k,2k+1.
// k bits: 4=q1, 2=q2, 1=q3; pack element = q4.

template<int Sk>
__device__ __forceinline__ void rx_pk(v2* R, v2* I, v2 c, v2 s, v2 ns) {
#pragma unroll
    for (int k = 0; k < 8; ++k) {
        if (k & Sk) continue;
        const int j = k + Sk;
        const v2 r0 = R[k], i0 = I[k], r1 = R[j], i1 = I[j];
        R[k] = vfma(c, r0, s * i1);
        I[k] = vfma(c, i0, ns * r1);
        R[j] = vfma(c, r1, s * i0);
        I[j] = vfma(c, i1, ns * r0);
    }
}

// RX on q4: partner is the other pack element (.yx folds to op_sel).
__device__ __forceinline__ void rx_q4(v2* R, v2* I, v2 c, v2 s, v2 ns) {
#pragma unroll
    for (int k = 0; k < 8; ++k) {
        const v2 r = R[k], i = I[k];
        R[k] = vfma(c, r, s * i.yx);
        I[k] = vfma(c, i, ns * r.yx);
    }
}

// CX^e with control k-bit Sck, target k-bit Stk. u = B*(a1-a0); a0+=u; a1-=u.
template<int Sck, int Stk>
__device__ __forceinline__ void cx_pk(v2* R, v2* I, v2 br, v2 bi, v2 nbi) {
#pragma unroll
    for (int k = 0; k < 8; ++k) {
        if (!(k & Sck) || (k & Stk)) continue;
        const int j = k + Stk;
        const v2 dr = R[j] - R[k], di = I[j] - I[k];
        const v2 ur = vfma(br, dr, nbi * di);
        const v2 ui = vfma(br, di, bi * dr);
        R[k] += ur; I[k] += ui;
        R[j] -= ur; I[j] -= ui;
    }
}

// CX^e control q3 (k-bit 1), target q4 (pack element): d=(a1-a0,a0-a1) via .yx.
__device__ __forceinline__ void cx_q3q4(v2* R, v2* I, v2 br, v2 bi, v2 nbi) {
#pragma unroll
    for (int k = 1; k < 8; k += 2) {
        const v2 dr = R[k].yx - R[k], di = I[k].yx - I[k];
        const v2 ur = vfma(br, dr, nbi * di);
        const v2 ui = vfma(br, di, bi * dr);
        R[k] += ur; I[k] += ui;
    }
}

// CX^e control q4 (pack element 1), target q1 (k-bit 4): mask in coefficient.
__device__ __forceinline__ void cx_q4q1(v2* R, v2* I, v2 brm, v2 bim, v2 nbim) {
#pragma unroll
    for (int k = 0; k < 4; ++k) {
        const int j = k + 4;
        const v2 dr = R[j] - R[k], di = I[j] - I[k];
        const v2 ur = vfma(brm, dr, nbim * di);
        const v2 ui = vfma(brm, di, bim * dr);
        R[k] += ur; I[k] += ui;
        R[j] -= ur; I[j] -= ui;
    }
}

// Phase (cl,sl) on q1=1 packs (k>=4). Pass (1,0) for identity (psi0 lane).
__device__ __forceinline__ void cz_pk(v2* R, v2* I, v2 cl, v2 sl, v2 nsl) {
#pragma unroll
    for (int k = 4; k < 8; ++k) {
        const v2 r = R[k], i = I[k];
        R[k] = vfma(cl, r, nsl * i);
        I[k] = vfma(sl, r, cl * i);
    }
}

// Block = 256 threads = 128 sims (16 pixels x 8 rows) x 2 lanes (psi0/psi1).
// Phase 1 fills LDS tables (312 entries); phase 2 evolves ONE half-state per
// thread (halved critical path vs r7), cross-lane dot via shfl_xor(1).
__global__ __launch_bounds__(256)
void u1_split_pk_kernel(const float* __restrict__ inp,   // (32,32,32,3)
                        const float* __restrict__ ker,   // (8,1,15)
                        float* __restrict__ out) {       // (32,31,31,8)
    const int tid = threadIdx.x;
    const int blockPix0 = blockIdx.x * 16;

    // trig[pl][j*4+c] = (cos,sin)(a*0.25); coef[r][5j+g] = (br,bi) g<4, (cl,sl) g=4.
    __shared__ v2 trig[16][12];
    __shared__ v2 coef[8][15];

#pragma unroll
    for (int pass = 0; pass < 2; ++pass) {
        const int e = tid + pass * 256;
        if (e < 192) {
            const int pl = e / 12;
            const int s  = e % 12;
            const int j  = s >> 2;
            const int c  = s & 3;
            const int pix = blockPix0 + pl;
            const int iy = pix % 31;
            const int tq = pix / 31;
            const int ix = tq % 31;
            const int b  = tq / 31;
            const float a = inp[((size_t)(b * 32 + ix + (c >> 1)) * 32
                                 + (iy + (c & 1))) * 3 + j];
            v2 cs;
            cs.x = __builtin_amdgcn_cosf(a * 0.25f);
            cs.y = __builtin_amdgcn_sinf(a * 0.25f);
            trig[pl][s] = cs;
        } else if (e < 312) {
            const int ec = e - 192;
            const int r  = ec / 15;
            const int g  = ec % 15;
            const float p = ker[r * 15 + g];
            const float rev = p * 0.5f;
            const float cl = __builtin_amdgcn_cosf(rev);
            const float sl = __builtin_amdgcn_sinf(rev);
            v2 cf;
            if (g % 5 == 4) { cf.x = cl; cf.y = sl; }                  // CZ
            else { cf.x = 0.5f * (1.0f - cl); cf.y = -0.5f * sl; }     // CX B
            coef[r][g] = cf;
        }
    }
    __syncthreads();

    const int h  = tid & 1;        // 0: psi0 lane, 1: psi1 lane
    const int g  = tid >> 1;       // local sim
    const int r  = g & 7;
    const int pl = g >> 3;
    const v2* T = trig[pl];
    const v2* Q = coef[r];

    // ---------- layer 0: RX product state on q1..q4 (q0 analytic)
    const v2 cs1 = T[0], cs2 = T[1], cs3 = T[2], cs4 = T[3];
    float t2[4], t3[8];
    t2[0] = cs1.x * cs2.x; t2[1] = cs1.x * cs2.y;
    t2[2] = cs1.y * cs2.x; t2[3] = cs1.y * cs2.y;
#pragma unroll
    for (int x = 0; x < 8; ++x) t3[x] = t2[x >> 1] * ((x & 1) ? cs3.y : cs3.x);

    // amp(m) = (-i)^popcount(m) * mag(m): one real + one imag elem per pack.
    v2 R[8], I[8];
#pragma unroll
    for (int k = 0; k < 8; ++k) {
        const int pc = __builtin_popcount(k) & 3;
        const v2 mg = cs4 * sp(t3[k]);
        v2 rr, ii;
        if (pc == 0)      { rr.x =  mg.x; rr.y = 0.0f;  ii.x = 0.0f;  ii.y = -mg.y; }
        else if (pc == 1) { rr.x = 0.0f;  rr.y = -mg.y; ii.x = -mg.x; ii.y = 0.0f;  }
        else if (pc == 2) { rr.x = -mg.x; rr.y = 0.0f;  ii.x = 0.0f;  ii.y =  mg.y; }
        else              { rr.x = 0.0f;  rr.y =  mg.y; ii.x =  mg.x; ii.y = 0.0f;  }
        R[k] = rr; I[k] = ii;
    }

    // ---------- all 3 layers: RX (layers 1-2) + entanglers + lane-masked CZ
#pragma unroll
    for (int j = 0; j < 3; ++j) {
        if (j > 0) {
            const v2* Tj = T + 4 * j;
            v2 cs;
            cs = Tj[0]; rx_pk<4>(R, I, sp(cs.x), sp(cs.y), sp(-cs.y));
            cs = Tj[1]; rx_pk<2>(R, I, sp(cs.x), sp(cs.y), sp(-cs.y));
            cs = Tj[2]; rx_pk<1>(R, I, sp(cs.x), sp(cs.y), sp(-cs.y));
            cs = Tj[3]; rx_q4  (R, I, sp(cs.x), sp(cs.y), sp(-cs.y));
        }
        const v2* Qj = Q + 5 * j;
        v2 q;
        q = Qj[0]; cx_pk<4, 2>(R, I, sp(q.x), sp(q.y), sp(-q.y));
        q = Qj[1]; cx_pk<2, 1>(R, I, sp(q.x), sp(q.y), sp(-q.y));
        q = Qj[2]; cx_q3q4 (R, I, sp(q.x), sp(q.y), sp(-q.y));
        q = Qj[3];
        {
            v2 brm, bim, nbim;
            brm.x = 0.0f; brm.y = q.x;
            bim.x = 0.0f; bim.y = q.y;
            nbim.x = 0.0f; nbim.y = -q.y;
            cx_q4q1(R, I, brm, bim, nbim);
        }
        // CZ: psi1 lane gets the phase, psi0 lane identity (branchless).
        q = Qj[4];
        const float cl = h ? q.x : 1.0f;
        const float sl = h ? q.y : 0.0f;
        cz_pk(R, I, sp(cl), sp(sl), sp(-sl));
    }

    // <X0> = sum Re(conj(psi0)*psi1): products are lane-symmetric, so both
    // lanes compute the full dot from partner values via shfl_xor(1).
    v2 acc = sp(0.0f);
#pragma unroll
    for (int k = 0; k < 8; ++k) {
        v2 pr, pi;
        pr.x = __shfl_xor(R[k].x, 1); pr.y = __shfl_xor(R[k].y, 1);
        pi.x = __shfl_xor(I[k].x, 1); pi.y = __shfl_xor(I[k].y, 1);
        acc = vfma(R[k], pr, vfma(I[k], pi, acc));
    }
    const float dot = acc.x + acc.y;

    // acos(x)/pi via A&S 4.4.45 (err < 6.7e-5 rad)
    float x = fminf(fmaxf(dot, -1.0f + 1e-5f), 1.0f - 1e-5f);
    const float a  = fabsf(x);
    const float sq = __builtin_amdgcn_sqrtf(1.0f - a);
    float pq = fmaf(a, -0.0187293f, 0.0742610f);
    pq = fmaf(a, pq, -0.2121144f);
    pq = fmaf(a, pq, 1.5707288f);
    float ac = sq * pq;
    if (x < 0.0f) ac = PI_F - ac;

    if (h == 0) out[blockIdx.x * 128 + g] = ac * (1.0f / PI_F);
}

extern "C" void kernel_launch(void* const* d_in, const int* in_sizes, int n_in,
                              void* d_out, int out_size, void* d_ws, size_t ws_size,
                              hipStream_t stream) {
    const float* inp = (const float*)d_in[0];   // (32,32,32,3) fp32
    const float* ker = (const float*)d_in[1];   // (8,1,15)     fp32
    float* out = (float*)d_out;                 // (32,31,31,8) fp32
    const int grid = out_size / 128;            // 1922, exact (246016 = 1922*128)
    u1_split_pk_kernel<<<grid, 256, 0, stream>>>(inp, ker, out);
}

// Round 9
// 64.091 us; speedup vs baseline: 1.0770x; 1.0770x over previous
//
#include <hip/hip_runtime.h>
#include <math.h>

#define PI_F 3.14159265358979323846f

typedef float v2 __attribute__((ext_vector_type(2)));

__device__ __forceinline__ v2 sp(float x) { v2 r; r.x = x; r.y = x; return r; }
__device__ __forceinline__ v2 vfma(v2 a, v2 b, v2 c) {
    return __builtin_elementwise_fma(a, b, c);
}

// State: 16 complex amps per half, packed along q4: pack k holds amps m=2k,2k+1.
// k bits: 4=q1, 2=q2, 1=q3; pack element = q4.

template<int Sk>
__device__ __forceinline__ void rx_pk(v2* R, v2* I, v2 c, v2 s, v2 ns) {
#pragma unroll
    for (int k = 0; k < 8; ++k) {
        if (k & Sk) continue;
        const int j = k + Sk;
        const v2 r0 = R[k], i0 = I[k], r1 = R[j], i1 = I[j];
        R[k] = vfma(c, r0, s * i1);
        I[k] = vfma(c, i0, ns * r1);
        R[j] = vfma(c, r1, s * i0);
        I[j] = vfma(c, i1, ns * r0);
    }
}

// RX on q4: partner is the other pack element (.yx folds to op_sel).
__device__ __forceinline__ void rx_q4(v2* R, v2* I, v2 c, v2 s, v2 ns) {
#pragma unroll
    for (int k = 0; k < 8; ++k) {
        const v2 r = R[k], i = I[k];
        R[k] = vfma(c, r, s * i.yx);
        I[k] = vfma(c, i, ns * r.yx);
    }
}

// CX^e with control k-bit Sck, target k-bit Stk. u = B*(a1-a0); a0+=u; a1-=u.
template<int Sck, int Stk>
__device__ __forceinline__ void cx_pk(v2* R, v2* I, v2 br, v2 bi, v2 nbi) {
#pragma unroll
    for (int k = 0; k < 8; ++k) {
        if (!(k & Sck) || (k & Stk)) continue;
        const int j = k + Stk;
        const v2 dr = R[j] - R[k], di = I[j] - I[k];
        const v2 ur = vfma(br, dr, nbi * di);
        const v2 ui = vfma(br, di, bi * dr);
        R[k] += ur; I[k] += ui;
        R[j] -= ur; I[j] -= ui;
    }
}

// CX^e control q3 (k-bit 1), target q4 (pack element): d=(a1-a0,a0-a1) via .yx.
__device__ __forceinline__ void cx_q3q4(v2* R, v2* I, v2 br, v2 bi, v2 nbi) {
#pragma unroll
    for (int k = 1; k < 8; k += 2) {
        const v2 dr = R[k].yx - R[k], di = I[k].yx - I[k];
        const v2 ur = vfma(br, dr, nbi * di);
        const v2 ui = vfma(br, di, bi * dr);
        R[k] += ur; I[k] += ui;
    }
}

// CX^e control q4 (pack element 1), target q1 (k-bit 4): mask in coefficient.
__device__ __forceinline__ void cx_q4q1(v2* R, v2* I, v2 brm, v2 bim, v2 nbim) {
#pragma unroll
    for (int k = 0; k < 4; ++k) {
        const int j = k + 4;
        const v2 dr = R[j] - R[k], di = I[j] - I[k];
        const v2 ur = vfma(brm, dr, nbim * di);
        const v2 ui = vfma(brm, di, bim * dr);
        R[k] += ur; I[k] += ui;
        R[j] -= ur; I[j] -= ui;
    }
}

// Phase lam=(cl,sl) on q1=1 packs (k>=4) — psi1 only.
__device__ __forceinline__ void cz_pk(v2* R, v2* I, v2 cl, v2 sl, v2 nsl) {
#pragma unroll
    for (int k = 4; k < 8; ++k) {
        const v2 r = R[k], i = I[k];
        R[k] = vfma(cl, r, nsl * i);
        I[k] = vfma(sl, r, cl * i);
    }
}

// Block = 32 pixels x 8 rows. Phase 1 fills LDS tables (504 entries, <=2 per
// thread); phase 2 is the packed gate chain reading coefficients from LDS.
__global__ __launch_bounds__(256)
void u1_lds_kernel(const float* __restrict__ inp,   // (32,32,32,3)
                   const float* __restrict__ ker,   // (8,1,15)
                   float* __restrict__ out) {       // (32,31,31,8)
    const int tid = threadIdx.x;
    const int blockPix0 = blockIdx.x * 32;

    // trig[pl][j*4+c] = (cos, sin)(a*0.25) for pixel-local pl, channel j,
    // corner c (offsets {0,3,96,99}); coef[r][5j+g] = (br,bi) g<4, (cl,sl) g=4.
    __shared__ v2 trig[32][12];
    __shared__ v2 coef[8][15];

#pragma unroll
    for (int pass = 0; pass < 2; ++pass) {
        const int e = tid + pass * 256;
        if (e < 384) {
            const int pl = e / 12;
            const int s  = e % 12;
            const int j  = s >> 2;
            const int c  = s & 3;
            const int pix = blockPix0 + pl;
            const int iy = pix % 31;
            const int tq = pix / 31;
            const int ix = tq % 31;
            const int b  = tq / 31;
            const float a = inp[((size_t)(b * 32 + ix + (c >> 1)) * 32
                                 + (iy + (c & 1))) * 3 + j];
            v2 cs;
            cs.x = __builtin_amdgcn_cosf(a * 0.25f);
            cs.y = __builtin_amdgcn_sinf(a * 0.25f);
            trig[pl][s] = cs;
        } else if (e < 504) {
            const int ec = e - 384;
            const int r  = ec / 15;
            const int g  = ec % 15;
            const float p = ker[r * 15 + g];
            const float rev = p * 0.5f;
            const float cl = __builtin_amdgcn_cosf(rev);
            const float sl = __builtin_amdgcn_sinf(rev);
            v2 cf;
            if (g % 5 == 4) { cf.x = cl; cf.y = sl; }                  // CZ
            else { cf.x = 0.5f * (1.0f - cl); cf.y = -0.5f * sl; }     // CX B
            coef[r][g] = cf;
        }
    }
    __syncthreads();

    const int r  = tid & 7;
    const int pl = tid >> 3;
    const v2* T = trig[pl];
    const v2* Q = coef[r];

    // ---------- layer 0: RX product state on q1..q4 (q0 analytic)
    const v2 cs1 = T[0], cs2 = T[1], cs3 = T[2], cs4 = T[3];
    float t2[4], t3[8];
    t2[0] = cs1.x * cs2.x; t2[1] = cs1.x * cs2.y;
    t2[2] = cs1.y * cs2.x; t2[3] = cs1.y * cs2.y;
#pragma unroll
    for (int x = 0; x < 8; ++x) t3[x] = t2[x >> 1] * ((x & 1) ? cs3.y : cs3.x);

    // amp(m) = (-i)^popcount(m) * mag(m): one real + one imag elem per pack.
    v2 R0[8], I0[8], R1[8], I1[8];
#pragma unroll
    for (int k = 0; k < 8; ++k) {
        const int pc = __builtin_popcount(k) & 3;
        const v2 mg = cs4 * sp(t3[k]);
        v2 rr, ii;
        if (pc == 0)      { rr.x =  mg.x; rr.y = 0.0f;  ii.x = 0.0f;  ii.y = -mg.y; }
        else if (pc == 1) { rr.x = 0.0f;  rr.y = -mg.y; ii.x = -mg.x; ii.y = 0.0f;  }
        else if (pc == 2) { rr.x = -mg.x; rr.y = 0.0f;  ii.x = 0.0f;  ii.y =  mg.y; }
        else              { rr.x = 0.0f;  rr.y =  mg.y; ii.x =  mg.x; ii.y = 0.0f;  }
        R0[k] = rr; I0[k] = ii;
    }

    {
        v2 q;
        q = Q[0]; cx_pk<4, 2>(R0, I0, sp(q.x), sp(q.y), sp(-q.y));
        q = Q[1]; cx_pk<2, 1>(R0, I0, sp(q.x), sp(q.y), sp(-q.y));
        q = Q[2]; cx_q3q4 (R0, I0, sp(q.x), sp(q.y), sp(-q.y));
        q = Q[3];
        v2 brm, bim, nbim;
        brm.x = 0.0f; brm.y = q.x;
        bim.x = 0.0f; bim.y = q.y;
        nbim.x = 0.0f; nbim.y = -q.y;
        cx_q4q1(R0, I0, brm, bim, nbim);
    }

    // first CZ: psi1 = psi0 with phase on q1=1 packs; psi0 unchanged.
    {
        const v2 zq = Q[4];
        const v2 clv = sp(zq.x), slv = sp(zq.y), nslv = sp(-zq.y);
#pragma unroll
        for (int k = 0; k < 4; ++k) { R1[k] = R0[k]; I1[k] = I0[k]; }
#pragma unroll
        for (int k = 4; k < 8; ++k) {
            R1[k] = vfma(clv, R0[k], nslv * I0[k]);
            I1[k] = vfma(slv, R0[k], clv * I0[k]);
        }
    }

    // ---------- layers 1..2: identical RX/CX on both halves; CZ on psi1 only
#pragma unroll
    for (int j = 1; j < 3; ++j) {
        const v2* Tj = T + 4 * j;
        v2 cs;
        cs = Tj[0];
        rx_pk<4>(R0, I0, sp(cs.x), sp(cs.y), sp(-cs.y));
        rx_pk<4>(R1, I1, sp(cs.x), sp(cs.y), sp(-cs.y));
        cs = Tj[1];
        rx_pk<2>(R0, I0, sp(cs.x), sp(cs.y), sp(-cs.y));
        rx_pk<2>(R1, I1, sp(cs.x), sp(cs.y), sp(-cs.y));
        cs = Tj[2];
        rx_pk<1>(R0, I0, sp(cs.x), sp(cs.y), sp(-cs.y));
        rx_pk<1>(R1, I1, sp(cs.x), sp(cs.y), sp(-cs.y));
        cs = Tj[3];
        rx_q4  (R0, I0, sp(cs.x), sp(cs.y), sp(-cs.y));
        rx_q4  (R1, I1, sp(cs.x), sp(cs.y), sp(-cs.y));

        const v2* Qj = Q + 5 * j;
        v2 q;
        q = Qj[0];
        cx_pk<4, 2>(R0, I0, sp(q.x), sp(q.y), sp(-q.y));
        cx_pk<4, 2>(R1, I1, sp(q.x), sp(q.y), sp(-q.y));
        q = Qj[1];
        cx_pk<2, 1>(R0, I0, sp(q.x), sp(q.y), sp(-q.y));
        cx_pk<2, 1>(R1, I1, sp(q.x), sp(q.y), sp(-q.y));
        q = Qj[2];
        cx_q3q4(R0, I0, sp(q.x), sp(q.y), sp(-q.y));
        cx_q3q4(R1, I1, sp(q.x), sp(q.y), sp(-q.y));
        q = Qj[3];
        {
            v2 brm, bim, nbim;
            brm.x = 0.0f; brm.y = q.x;
            bim.x = 0.0f; bim.y = q.y;
            nbim.x = 0.0f; nbim.y = -q.y;
            cx_q4q1(R0, I0, brm, bim, nbim);
            cx_q4q1(R1, I1, brm, bim, nbim);
        }
        q = Qj[4];
        cz_pk(R1, I1, sp(q.x), sp(q.y), sp(-q.y));
    }

    // <X0> = sum Re(conj(psi0)*psi1)  (1/sqrt2 factors cancel the 2x)
    v2 acc = sp(0.0f);
#pragma unroll
    for (int k = 0; k < 8; ++k)
        acc = vfma(R0[k], R1[k], vfma(I0[k], I1[k], acc));
    const float dot = acc.x + acc.y;

    // acos(x)/pi via A&S 4.4.45 (err < 6.7e-5 rad)
    float x = fminf(fmaxf(dot, -1.0f + 1e-5f), 1.0f - 1e-5f);
    const float a  = fabsf(x);
    const float sq = __builtin_amdgcn_sqrtf(1.0f - a);
    float pq = fmaf(a, -0.0187293f, 0.0742610f);
    pq = fmaf(a, pq, -0.2121144f);
    pq = fmaf(a, pq, 1.5707288f);
    float ac = sq * pq;
    if (x < 0.0f) ac = PI_F - ac;

    out[blockIdx.x * 256 + tid] = ac * (1.0f / PI_F);
}

extern "C" void kernel_launch(void* const* d_in, const int* in_sizes, int n_in,
                              void* d_out, int out_size, void* d_ws, size_t ws_size,
                              hipStream_t stream) {
    const float* inp = (const float*)d_in[0];   // (32,32,32,3) fp32
    const float* ker = (const float*)d_in[1];   // (8,1,15)     fp32
    float* out = (float*)d_out;                 // (32,31,31,8) fp32
    const int grid = out_size / 256;            // 961, exact (246016 = 961*256)
    u1_lds_kernel<<<grid, 256, 0, stream>>>(inp, ker, out);
}